// Round 4
// baseline (210.161 us; speedup 1.0000x reference)
//
#include <hip/hip_runtime.h>
#include <hip/hip_bf16.h>
#include <math.h>

#define B_    16
#define M_    128
#define T_    2048
#define H_    512
#define TOUT_ 2049

typedef unsigned short u16;
typedef unsigned int   u32;
typedef __bf16 bf16x8 __attribute__((ext_vector_type(8)));
typedef float  f32x16 __attribute__((ext_vector_type(16)));
typedef float  f32x4  __attribute__((ext_vector_type(4)));
typedef u32    u32x4  __attribute__((ext_vector_type(4)));
typedef u32    u32x2  __attribute__((ext_vector_type(2)));

// ws layout (float units):
#define A_OFF     0                       // fp32 Ao only [128][128]
#define C_OFF     16384                   // c[3][128]
#define MEAN_OFF  16896                   // meanv [2048]
#define AQKBF_OFF 19200                   // u16 [256][128] = 16384 fl
#define AOBF_OFF  35584                   // u16 [128][128] = 8192 fl
#define QT_OFF    43776
#define KT_OFF    (43776 + 2097152)
#define VB_OFF    (43776 + 2 * 2097152)

static __device__ __forceinline__ u16 f2bf(float f) {
  u32 u = __float_as_uint(f);
  u = (u + 0x7FFFu + ((u >> 16) & 1u)) >> 16;
  return (u16)u;
}
static __device__ __forceinline__ u32 pk2(float lo, float hi) {
  __hip_bfloat162 h = __float22bfloat162_rn(float2{lo, hi});
  u32 r;
  __builtin_memcpy(&r, &h, 4);
  return r;
}
static __device__ __forceinline__ bf16x8 ldfrag(const u16* p) {
  return __builtin_bit_cast(bf16x8, *(const u32x4*)p);
}
static __device__ __forceinline__ float ex2(float x) {
#if __has_builtin(__builtin_amdgcn_exp2f)
  return __builtin_amdgcn_exp2f(x);  // v_exp_f32 = 2^x
#else
  return exp2f(x);
#endif
}

// ---------------------------------------------------------------------------
__global__ __launch_bounds__(128) void fuse_weights_all(
    const float* __restrict__ W1q, const float* __restrict__ b1q,
    const float* __restrict__ W2q, const float* __restrict__ b2q,
    const float* __restrict__ W1k, const float* __restrict__ b1k,
    const float* __restrict__ W2k, const float* __restrict__ b2k,
    const float* __restrict__ W1o, const float* __restrict__ b1o,
    const float* __restrict__ W2o, const float* __restrict__ b2o,
    float* __restrict__ A, float* __restrict__ c,
    u16* __restrict__ Aqk_bf, u16* __restrict__ Ao_bf) {
  __shared__ float w2row[H_];
  int which = blockIdx.x >> 7;
  int o = blockIdx.x & 127;
  const float* W1 = which == 0 ? W1q : which == 1 ? W1k : W1o;
  const float* b1 = which == 0 ? b1q : which == 1 ? b1k : b1o;
  const float* W2 = which == 0 ? W2q : which == 1 ? W2k : W2o;
  const float* b2 = which == 0 ? b2q : which == 1 ? b2k : b2o;
  int m = threadIdx.x;
  for (int h = m; h < H_; h += 128) w2row[h] = W2[o * H_ + h];
  __syncthreads();
  float acc = 0.f;
#pragma unroll 8
  for (int h = 0; h < H_; ++h) acc = fmaf(w2row[h], W1[h * M_ + m], acc);
  u16 ab = f2bf(acc);
  if (which == 0)      Aqk_bf[o * 128 + m] = ab;
  else if (which == 1) Aqk_bf[(128 + o) * 128 + m] = ab;
  else               { Ao_bf[o * 128 + m] = ab; A[o * M_ + m] = acc; }
  if (m < 64) {
    float cc = 0.f;
    for (int h = m; h < H_; h += 64) cc = fmaf(w2row[h], b1[h], cc);
#pragma unroll
    for (int off = 32; off > 0; off >>= 1) cc += __shfl_down(cc, off, 64);
    if (m == 0) c[which * 128 + o] = cc + b2[o];
  }
}

// ---------------------------------------------------------------------------
// prep: blocks [0,512) = q/k MLP (MFMA, coalesced I/O);
//       blocks [512,2560) = value cast + windowed mean
// q outputs (o<128) pre-scaled by log2(e): exp(exp(qk)) =
// exp2(exp2(qk*log2e + log2(log2e))).
#define XS 68

__global__ __launch_bounds__(256) void prep_kernel(
    const float* __restrict__ pattern, const u16* __restrict__ Aqk_bf,
    const float* __restrict__ cqk, u16* __restrict__ qT, u16* __restrict__ kT,
    const float* __restrict__ value, u16* __restrict__ vb,
    float* __restrict__ meanv) {
  __shared__ alignas(16) float xsf[128 * XS];
  int bx = blockIdx.x;
  int tid = threadIdx.x;

  if (bx >= 512) {
    int bm = bx - 512;
    float* red = xsf;
    const float* row = value + (size_t)bm * T_;
    int i0 = tid * 8;
    float4 a = *(const float4*)(row + i0);
    float4 bq = *(const float4*)(row + i0 + 4);
    u32x4 o = {pk2(a.x, a.y), pk2(a.z, a.w), pk2(bq.x, bq.y), pk2(bq.z, bq.w)};
    *(u32x4*)&vb[(size_t)bm * T_ + i0] = o;
    float vals[8] = {a.x, a.y, a.z, a.w, bq.x, bq.y, bq.z, bq.w};
    float s = 0.f;
#pragma unroll
    for (int j = 0; j < 8; ++j) {
      int idx = i0 + j;
      if (idx >= 33 && idx < T_ - 1) s += vals[j];
    }
    red[tid] = s;
    __syncthreads();
    for (int st = 128; st > 0; st >>= 1) {
      if (tid < st) red[tid] += red[tid + st];
      __syncthreads();
    }
    if (tid == 0) meanv[bm] = red[0] * (1.f / 2014.f);
    return;
  }

  int b = bx >> 5;
  int t0 = (bx & 31) * 64;
  int lane = tid & 63;
  int wv = tid >> 6;
  int l31 = lane & 31;
  int lh8 = (lane >> 5) * 8;

  bf16x8 afr[2][8];
#pragma unroll
  for (int i = 0; i < 2; ++i) {
    const u16* ap = Aqk_bf + ((2 * wv + i) * 32 + l31) * 128 + lh8;
#pragma unroll
    for (int s = 0; s < 8; ++s) afr[i][s] = ldfrag(ap + 16 * s);
  }

#pragma unroll
  for (int rep = 0; rep < 8; ++rep) {
    int m = rep * 16 + (tid >> 4);
    int tc = (tid & 15) * 4;
    float4 v = *(const float4*)&pattern[(size_t)(b * M_ + m) * T_ + t0 + tc];
    *(float4*)&xsf[m * XS + tc] = v;
  }
  __syncthreads();

  bf16x8 bfr[2][8];
#pragma unroll
  for (int tt = 0; tt < 2; ++tt) {
#pragma unroll
    for (int s = 0; s < 8; ++s) {
      float v0 = xsf[(s * 16 + lh8 + 0) * XS + tt * 32 + l31];
      float v1 = xsf[(s * 16 + lh8 + 1) * XS + tt * 32 + l31];
      float v2 = xsf[(s * 16 + lh8 + 2) * XS + tt * 32 + l31];
      float v3 = xsf[(s * 16 + lh8 + 3) * XS + tt * 32 + l31];
      float v4 = xsf[(s * 16 + lh8 + 4) * XS + tt * 32 + l31];
      float v5 = xsf[(s * 16 + lh8 + 5) * XS + tt * 32 + l31];
      float v6 = xsf[(s * 16 + lh8 + 6) * XS + tt * 32 + l31];
      float v7 = xsf[(s * 16 + lh8 + 7) * XS + tt * 32 + l31];
      u32x4 p = {pk2(v0, v1), pk2(v2, v3), pk2(v4, v5), pk2(v6, v7)};
      bfr[tt][s] = __builtin_bit_cast(bf16x8, p);
    }
  }
  __syncthreads();  // xsf dead -> obuf

  u16* obuf = (u16*)xsf;  // [64 t][258 o]
#pragma unroll
  for (int tt = 0; tt < 2; ++tt) {
#pragma unroll
    for (int i = 0; i < 2; ++i) {
      f32x16 acc;
#pragma unroll
      for (int r = 0; r < 16; ++r) acc[r] = 0.f;
#pragma unroll
      for (int s = 0; s < 8; ++s)
        acc = __builtin_amdgcn_mfma_f32_32x32x16_bf16(afr[i][s], bfr[tt][s], acc, 0, 0, 0);
      int ot = 2 * wv + i;
      int t = tt * 32 + l31;
      float sc = (ot < 4) ? 1.44269504f : 1.0f;  // scale q (o<128) by log2e
#pragma unroll
      for (int r = 0; r < 16; ++r) {
        int orow = (r & 3) + 8 * (r >> 2) + 4 * (lane >> 5);
        float v = acc[r] + cqk[ot * 32 + orow];
        v = v > 0.f ? v : 0.01f * v;
        obuf[t * 258 + ot * 32 + orow] = f2bf(v * sc);
      }
    }
  }
  __syncthreads();

  const u32* ob32 = (const u32*)obuf;
#pragma unroll
  for (int g = 0; g < 8; ++g) {
    int G = wv * 8 + g;
    int mat = G >> 4;
    int t = (G & 15) * 4 + (lane >> 4);
    int og2 = lane & 15;
    int wbase = t * 129 + mat * 64 + og2 * 4;
    u32x4 vv = {ob32[wbase], ob32[wbase + 1], ob32[wbase + 2], ob32[wbase + 3]};
    u32* dst = (u32*)((mat ? kT : qT) + ((size_t)(b * T_ + t0 + t)) * 128) + og2 * 4;
    *(u32x4*)dst = vv;
  }
}

// ---------------------------------------------------------------------------
// attn v10: OCCUPANCY. Same grid (256 blocks, 128 q each, 1 block/CU, same
// global + staging traffic) but 1024 threads = 16 waves = 4 waves/SIMD
// (v6-v9 all ran 2/SIMD; three structural nulls showed latency-hiding, not
// work, is the binder). Waves: qt(4: 32-q tile) x kh(2: 32-k half of 64-k
// tile) x mh(2: 64-m half of PV). pacc[2] (32 VGPR) keeps per-wave regs
// under the 128 cap that 4 waves/SIMD requires. Staging split 1024 ways
// (1 u32x4 K + 1 V per thread), KTILE=64 dbuf, single barrier/tile.
#define QSTR 136  // u16: 68 words == 4 mod 32 (conflict-free)
#define VSTR 72   // u16: 36 words == 4 mod 32
#define KTILE 64
#define NKT  (T_ / KTILE)
#define CINIT 0.52876637f   // log2(log2 e)

__global__ __launch_bounds__(1024, 4) void attn_mfma_kernel(
    const u16* __restrict__ qT, const u16* __restrict__ kT,
    const u16* __restrict__ vB, const u16* __restrict__ Ao_bf,
    const float* __restrict__ co, const float* __restrict__ Aofp,
    const float* __restrict__ meanv, float* __restrict__ out) {
  extern __shared__ u16 smem[];
  // loop: ks dbuf [64][QSTR] x2 (34,816 B) + vs dbuf [128][VSTR] x2 (36,864 B)
  u16* ks0 = smem;
  u16* ks1 = smem + 8704;
  u16* vs0 = smem + 17408;
  u16* vs1 = smem + 26624;
  // epilogue aliases (loop buffers dead after E1):
  float* pbuf  = (float*)smem;             // 65,536 B: kh==1 partials
  u16*   ptbuf = smem + 33024;             // [128][QSTR] 34,816 B: P^T bf16
  float* dls   = (float*)(smem + 50432);   // [128] (disjoint from both)

  int b = blockIdx.y;
  int q0 = blockIdx.x * 128;
  int tid = threadIdx.x;
  int lane = tid & 63;
  int wv = tid >> 6;                 // 0..15
  int l31 = lane & 31;
  int h = lane >> 5;
  int lh8 = h * 8;
  int qt = wv & 3;                   // q-tile (32 q's)
  int kh = (wv >> 2) & 1;            // 32-k half of the 64-k tile
  int mh = wv >> 3;                  // 64-m half for PV

  const u16* gkb = kT + (size_t)b * T_ * 128;
  const u16* gvb = vB + (size_t)b * M_ * T_;
  int kr = tid >> 4, kc = (tid & 15) * 8;   // K: [64 k][128 m] 1 vec/thread
  int vr = tid >> 3, vc = (tid & 7) * 8;    // V: [128 m][64 k] 1 vec/thread

  // persistent Q B-frags straight from global (one-time, L2-resident)
  bf16x8 qfrag[8];
  {
    const u16* qrow = qT + (size_t)(b * T_ + q0 + qt * 32 + l31) * 128 + lh8;
#pragma unroll
    for (int s = 0; s < 8; ++s) qfrag[s] = ldfrag(qrow + s * 16);
  }

  u32x4 kreg, vreg;
  kreg = *(const u32x4*)&gkb[(size_t)kr * 128 + kc];
  vreg = *(const u32x4*)&gvb[(size_t)vr * T_ + vc];
  *(u32x4*)&ks0[kr * QSTR + kc] = kreg;
  *(u32x4*)&vs0[vr * VSTR + vc] = vreg;
  kreg = *(const u32x4*)&gkb[(size_t)(KTILE + kr) * 128 + kc];
  vreg = *(const u32x4*)&gvb[(size_t)vr * T_ + KTILE + vc];

  f32x16 pacc[2];
  float den = 0.f;
#pragma unroll
  for (int i = 0; i < 16; ++i) { pacc[0][i] = 0.f; pacc[1][i] = 0.f; }

  for (int kt = 0; kt < NKT; ++kt) {
    u16* kcur = (kt & 1) ? ks1 : ks0;
    u16* knxt = (kt & 1) ? ks0 : ks1;
    u16* vcur = (kt & 1) ? vs1 : vs0;
    u16* vnxt = (kt & 1) ? vs0 : vs1;
    __syncthreads();  // staging(kt) visible; prev readers of nxt drained

    // stage tile kt+1; prefetch tile kt+2 (1 vec each, 1024 threads)
    if (kt < NKT - 1) {
      *(u32x4*)&knxt[kr * QSTR + kc] = kreg;
      *(u32x4*)&vnxt[vr * VSTR + vc] = vreg;
      int kn = (kt + 2 < NKT) ? (kt + 2) * KTILE : (NKT - 1) * KTILE;
      kreg = *(const u32x4*)&gkb[(size_t)(kn + kr) * 128 + kc];
      vreg = *(const u32x4*)&gvb[(size_t)vr * T_ + kn + vc];
    }

    // S'[k][q] = mfma(K, Q) over this wave's 32 k's
    f32x16 sacc;
#pragma unroll
    for (int i = 0; i < 16; ++i) sacc[i] = CINIT;
    {
      const u16* krow = &kcur[(kh * 32 + l31) * QSTR + lh8];
#pragma unroll
      for (int s = 0; s < 8; ++s) {
        bf16x8 kf = ldfrag(krow + s * 16);
        sacc = __builtin_amdgcn_mfma_f32_32x32x16_bf16(kf, qfrag[s], sacc, 0, 0, 0);
      }
    }

    // diagonal adjust (scaled domain): x -> x*d + C*(1-d)
    if (kt * KTILE + kh * 32 == q0 + qt * 32) {
#pragma unroll
      for (int r = 0; r < 16; ++r) {
        int row = (r & 3) + 8 * (r >> 2) + 4 * h;
        if (row == l31) sacc[r] = fmaf(sacc[r], 0.97790291f, 0.01168420f);
      }
    }

    // w = exp2(exp2(s')) == exp(exp(qk)); den; pack + half-wave exchange
    float w[16];
#pragma unroll
    for (int r = 0; r < 16; ++r) w[r] = ex2(ex2(sacc[r]));
    {
      float d0 = (w[0] + w[1]) + (w[2] + w[3]);
      float d1 = (w[4] + w[5]) + (w[6] + w[7]);
      float d2 = (w[8] + w[9]) + (w[10] + w[11]);
      float d3 = (w[12] + w[13]) + (w[14] + w[15]);
      den += (d0 + d1) + (d2 + d3);
    }
    u32 p00 = pk2(w[0], w[1]),  p01 = pk2(w[2], w[3]);
    u32 p10 = pk2(w[4], w[5]),  p11 = pk2(w[6], w[7]);
    u32 p20 = pk2(w[8], w[9]),  p21 = pk2(w[10], w[11]);
    u32 p30 = pk2(w[12], w[13]), p31 = pk2(w[14], w[15]);
    u32 e0 = __shfl_xor(h ? p00 : p10, 32, 64);
    u32 e1 = __shfl_xor(h ? p01 : p11, 32, 64);
    u32 e2 = __shfl_xor(h ? p20 : p30, 32, 64);
    u32 e3 = __shfl_xor(h ? p21 : p31, 32, 64);
    u32x4 f0 = h ? u32x4{e0, e1, p10, p11} : u32x4{p00, p01, e0, e1};
    u32x4 f1 = h ? u32x4{e2, e3, p30, p31} : u32x4{p20, p21, e2, e3};
    bf16x8 bw0 = __builtin_bit_cast(bf16x8, f0);
    bf16x8 bw1 = __builtin_bit_cast(bf16x8, f1);

    // PV partials: this wave's 32 k's, its 64 m's (2 m-tiles)
#pragma unroll
    for (int i = 0; i < 2; ++i) {
      int mtg = mh * 2 + i;
      const u16* vrow = &vcur[(mtg * 32 + l31) * VSTR + kh * 32 + lh8];
      bf16x8 vf0 = ldfrag(vrow);
      bf16x8 vf1 = ldfrag(vrow + 16);
      pacc[i] = __builtin_amdgcn_mfma_f32_32x32x16_bf16(vf0, bw0, pacc[i], 0, 0, 0);
      pacc[i] = __builtin_amdgcn_mfma_f32_32x32x16_bf16(vf1, bw1, pacc[i], 0, 0, 0);
    }
  }

  // per-q denominator for this wave's kh half (both h halves summed)
  float dq = den + __shfl_xor(den, 32, 64);

  __syncthreads();  // [E1] all loop reads done -> aliases safe

  if (kh == 1) {
#pragma unroll
    for (int i = 0; i < 2; ++i) {
      float* pb = &pbuf[(((qt * 2 + mh) * 2 + i) * 64 + lane) * 16];
#pragma unroll
      for (int g = 0; g < 4; ++g) {
        f32x4 v = {pacc[i][4 * g], pacc[i][4 * g + 1],
                   pacc[i][4 * g + 2], pacc[i][4 * g + 3]};
        *(f32x4*)(pb + 4 * g) = v;
      }
    }
    if (mh == 0 && lane < 32) dls[qt * 32 + lane] = dq;
  }
  __syncthreads();  // [E2]

  if (kh == 0) {
    float rden = 1.f / (dq + dls[qt * 32 + l31]);
#pragma unroll
    for (int i = 0; i < 2; ++i) {
      const float* pb = &pbuf[(((qt * 2 + mh) * 2 + i) * 64 + lane) * 16];
#pragma unroll
      for (int g = 0; g < 4; ++g) {
        f32x4 t = *(const f32x4*)(pb + 4 * g);
        float v0 = (pacc[i][4 * g + 0] + t[0]) * rden;
        float v1 = (pacc[i][4 * g + 1] + t[1]) * rden;
        float v2 = (pacc[i][4 * g + 2] + t[2]) * rden;
        float v3 = (pacc[i][4 * g + 3] + t[3]) * rden;
        int m0 = (mh * 2 + i) * 32 + 8 * g + 4 * h;
        u32x2 wp = {pk2(v0, v1), pk2(v2, v3)};
        *(u32x2*)&ptbuf[(qt * 32 + l31) * QSTR + m0] = wp;
      }
    }
  }
  __syncthreads();  // [E3] P^T visible

  // o-MLP epilogue: 16 waves = o-tile (wv&3) x q-tile (wv>>2), 8 MFMA each
  bf16x8 aofr[8];
  {
    const u16* ap = Ao_bf + ((wv & 3) * 32 + l31) * 128 + lh8;
#pragma unroll
    for (int s = 0; s < 8; ++s) aofr[s] = ldfrag(ap + 16 * s);
  }
  {
    int qt2 = wv >> 2;
    bf16x8 pfr[8];
    const u16* pp = &ptbuf[(qt2 * 32 + l31) * QSTR + lh8];
#pragma unroll
    for (int s = 0; s < 8; ++s) pfr[s] = ldfrag(pp + 16 * s);
    f32x16 oacc;
#pragma unroll
    for (int r = 0; r < 16; ++r) oacc[r] = 0.f;
#pragma unroll
    for (int s = 0; s < 8; ++s)
      oacc = __builtin_amdgcn_mfma_f32_32x32x16_bf16(aofr[s], pfr[s], oacc, 0, 0, 0);
#pragma unroll
    for (int r = 0; r < 16; ++r) {
      int orow = (wv & 3) * 32 + (r & 3) + 8 * (r >> 2) + 4 * h;
      float v = oacc[r] + co[orow];
      v = v > 0.f ? v : 0.01f * v;
      out[((size_t)(b * M_ + orow)) * TOUT_ + q0 + qt2 * 32 + l31] = v;
    }
  }

  // rep_ex tail
  if (blockIdx.x == 0 && tid < 128) {
    float acc = co[tid];
    const float* mv = meanv + b * 128;
    for (int m = 0; m < 128; ++m) acc = fmaf(Aofp[tid * 128 + m], mv[m], acc);
    acc = acc > 0.f ? acc : 0.01f * acc;
    out[((size_t)(b * M_ + tid)) * TOUT_ + 2048] = acc;
  }
}

// ---------------------------------------------------------------------------
extern "C" void kernel_launch(void* const* d_in, const int* in_sizes, int n_in,
                              void* d_out, int out_size, void* d_ws, size_t ws_size,
                              hipStream_t stream) {
  (void)in_sizes; (void)n_in; (void)out_size; (void)ws_size;
  const float* pattern = (const float*)d_in[0];
  const float* value   = (const float*)d_in[1];
  const float* Wq1 = (const float*)d_in[3];
  const float* bq1 = (const float*)d_in[4];
  const float* Wq2 = (const float*)d_in[5];
  const float* bq2 = (const float*)d_in[6];
  const float* Wk1 = (const float*)d_in[7];
  const float* bk1 = (const float*)d_in[8];
  const float* Wk2 = (const float*)d_in[9];
  const float* bk2 = (const float*)d_in[10];
  const float* Wo1 = (const float*)d_in[11];
  const float* bo1 = (const float*)d_in[12];
  const float* Wo2 = (const float*)d_in[13];
  const float* bo2 = (const float*)d_in[14];

  float* ws     = (float*)d_ws;
  float* A      = ws + A_OFF;
  float* c      = ws + C_OFF;
  float* meanv  = ws + MEAN_OFF;
  u16*   Aqk_bf = (u16*)(ws + AQKBF_OFF);
  u16*   Ao_bf  = (u16*)(ws + AOBF_OFF);
  u16*   qT     = (u16*)(ws + QT_OFF);
  u16*   kT     = (u16*)(ws + KT_OFF);
  u16*   vB     = (u16*)(ws + VB_OFF);
  float* out    = (float*)d_out;

  fuse_weights_all<<<384, 128, 0, stream>>>(
      Wq1, bq1, Wq2, bq2, Wk1, bk1, Wk2, bk2, Wo1, bo1, Wo2, bo2,
      A, c, Aqk_bf, Ao_bf);

  prep_kernel<<<512 + B_ * M_, 256, 0, stream>>>(
      pattern, Aqk_bf, c, qT, kT, value, vB, meanv);

  // LDS: loop 71,680 B (ks/vs dbuf); epilogue pbuf 65,536 + ptbuf 34,816
  // + dls 512 at offset 100,864 -> total 101,376 B (1 block/CU regardless)
  size_t lds_bytes = 101376;
  attn_mfma_kernel<<<dim3(T_ / 128, B_), 1024, lds_bytes, stream>>>(
      qT, kT, vB, Ao_bf, c + 256, A, meanv, out);
}